// Round 1
// baseline (626.074 us; speedup 1.0000x reference)
//
#include <hip/hip_runtime.h>
#include <math.h>

// Problem dims: x (2,1,160,160,16) f32, lambda (2,3,160,160,16) f32, 48 iters.
#define XDIM 160
#define YDIM 160
#define TDIM 16
#define NB 2
#define T_ITERS 48

constexpr int VOL = XDIM * YDIM * TDIM;   // 409600 per batch (x-shaped arrays)
constexpr int NX  = NB * VOL;             // 819200
constexpr int NQ  = NB * 3 * VOL;         // 2457600

__device__ __forceinline__ float clampl(float v, float l) {
    return fminf(fmaxf(v, -l), l);
}

__global__ __launch_bounds__(256) void init_kernel(
    const float* __restrict__ x, float* __restrict__ xbuf, float* __restrict__ p,
    float* __restrict__ xbarA, float* __restrict__ qA)
{
    int i = blockIdx.x * blockDim.x + threadIdx.x;
    if (i < NX) {
        float v = x[i];
        xbuf[i]  = v;   // x0 = x
        p[i]     = v;   // p = x
        xbarA[i] = v;   // xbar = x
    }
    if (i < NQ) qA[i] = 0.0f;  // q = 0
}

// One fused primal-dual iteration. Each thread processes 4 contiguous T elems.
__global__ __launch_bounds__(256) void step_kernel(
    const float* __restrict__ xn,         // xnoisy (original input)
    float* __restrict__ p,                // in-place pointwise
    const float* __restrict__ qin, float* __restrict__ qout,
    const float* __restrict__ x0buf, float* __restrict__ x1out,
    const float* __restrict__ xbin, float* __restrict__ xbout,
    const float* __restrict__ lam,
    float sigma, float inv1ps, float tau, float theta)
{
    int tid = blockIdx.x * blockDim.x + threadIdx.x;  // 0 .. NX/4-1
    if (tid >= NX / 4) return;

    const int t0    = (tid & 3) * 4;        // 0,4,8,12
    const int rest  = tid >> 2;             // b*XDIM*YDIM + xx*YDIM + yy
    const int yy    = rest % YDIM;
    const int rest2 = rest / YDIM;
    const int xx    = rest2 % XDIM;
    const int b     = rest2 / XDIM;

    const int xp = (xx == XDIM - 1) ? 0 : xx + 1;
    const int xm = (xx == 0) ? XDIM - 1 : xx - 1;
    const int yp = (yy == YDIM - 1) ? 0 : yy + 1;
    const int ym = (yy == 0) ? YDIM - 1 : yy - 1;

    const int sp    = xx * YDIM + yy;
    const int sp_xp = xp * YDIM + yy;
    const int sp_xm = xm * YDIM + yy;
    const int sp_yp = xx * YDIM + yp;
    const int sp_ym = xx * YDIM + ym;

    const int xbase = b * VOL;              // x-shaped arrays base for batch b
    const int qbase = b * 3 * VOL;          // q-shaped arrays base for batch b

    const int off    = xbase + sp * TDIM + t0;     // center, x-shaped
    const int lineof = xbase + sp * TDIM;          // line base for T wrap loads

    // --- xbar stencil loads ---
    const float4 xbC  = *(const float4*)(xbin + off);
    const float4 xbXP = *(const float4*)(xbin + xbase + sp_xp * TDIM + t0);
    const float4 xbXM = *(const float4*)(xbin + xbase + sp_xm * TDIM + t0);
    const float4 xbYP = *(const float4*)(xbin + xbase + sp_yp * TDIM + t0);
    const float4 xbYM = *(const float4*)(xbin + xbase + sp_ym * TDIM + t0);
    const float xb_tm = xbin[lineof + ((t0 + TDIM - 1) & (TDIM - 1))];
    const float xb_tp = xbin[lineof + ((t0 + 4) & (TDIM - 1))];

    const float4 xnC = *(const float4*)(xn    + off);
    const float4 pC  = *(const float4*)(p     + off);
    const float4 x0C = *(const float4*)(x0buf + off);

    // --- q / lambda loads (component d at offset d*VOL in q-shaped arrays) ---
    const int q0o = qbase + sp * TDIM + t0;
    const float4 q0C  = *(const float4*)(qin + q0o);
    const float4 q0XM = *(const float4*)(qin + qbase + sp_xm * TDIM + t0);
    const float4 q1C  = *(const float4*)(qin + q0o + VOL);
    const float4 q1YM = *(const float4*)(qin + qbase + VOL + sp_ym * TDIM + t0);
    const float4 q2C  = *(const float4*)(qin + q0o + 2 * VOL);
    const float  q2TM = qin[qbase + 2 * VOL + sp * TDIM + ((t0 + TDIM - 1) & (TDIM - 1))];

    const float4 l0C  = *(const float4*)(lam + q0o);
    const float4 l0XM = *(const float4*)(lam + qbase + sp_xm * TDIM + t0);
    const float4 l1C  = *(const float4*)(lam + q0o + VOL);
    const float4 l1YM = *(const float4*)(lam + qbase + VOL + sp_ym * TDIM + t0);
    const float4 l2C  = *(const float4*)(lam + q0o + 2 * VOL);
    const float  l2TM = lam[qbase + 2 * VOL + sp * TDIM + ((t0 + TDIM - 1) & (TDIM - 1))];

    // unpack to arrays for T-direction shifts
    float xbc[4]  = {xbC.x, xbC.y, xbC.z, xbC.w};
    float xbxp[4] = {xbXP.x, xbXP.y, xbXP.z, xbXP.w};
    float xbxm[4] = {xbXM.x, xbXM.y, xbXM.z, xbXM.w};
    float xbyp[4] = {xbYP.x, xbYP.y, xbYP.z, xbYP.w};
    float xbym[4] = {xbYM.x, xbYM.y, xbYM.z, xbYM.w};
    float xnc[4]  = {xnC.x, xnC.y, xnC.z, xnC.w};
    float pc[4]   = {pC.x, pC.y, pC.z, pC.w};
    float x0c[4]  = {x0C.x, x0C.y, x0C.z, x0C.w};
    float q0c[4]  = {q0C.x, q0C.y, q0C.z, q0C.w};
    float q0xm[4] = {q0XM.x, q0XM.y, q0XM.z, q0XM.w};
    float q1c[4]  = {q1C.x, q1C.y, q1C.z, q1C.w};
    float q1ym[4] = {q1YM.x, q1YM.y, q1YM.z, q1YM.w};
    float q2c[4]  = {q2C.x, q2C.y, q2C.z, q2C.w};
    float l0c[4]  = {l0C.x, l0C.y, l0C.z, l0C.w};
    float l0xm[4] = {l0XM.x, l0XM.y, l0XM.z, l0XM.w};
    float l1c[4]  = {l1C.x, l1C.y, l1C.z, l1C.w};
    float l1ym[4] = {l1YM.x, l1YM.y, l1YM.z, l1YM.w};
    float l2c[4]  = {l2C.x, l2C.y, l2C.z, l2C.w};

    float pn[4], q0n[4], q1n[4], q2n[4], x1v[4], xbn[4];

    #pragma unroll
    for (int j = 0; j < 4; ++j) {
        // p update (pointwise, new p used below)
        pn[j] = (pc[j] + sigma * (xbc[j] - xnc[j])) * inv1ps;

        // forward gradients of xbar at v
        float gx = xbxp[j] - xbc[j];
        float gy = xbyp[j] - xbc[j];
        float gt = ((j < 3) ? xbc[j + 1] : xb_tp) - xbc[j];

        // q_new at v
        q0n[j] = clampl(q0c[j] + sigma * gx, l0c[j]);
        q1n[j] = clampl(q1c[j] + sigma * gy, l1c[j]);
        q2n[j] = clampl(q2c[j] + sigma * gt, l2c[j]);

        // q_new at backward neighbors (recomputed)
        float q0m = clampl(q0xm[j] + sigma * (xbc[j] - xbxm[j]), l0xm[j]);
        float q1m = clampl(q1ym[j] + sigma * (xbc[j] - xbym[j]), l1ym[j]);
        float gtm  = xbc[j] - ((j == 0) ? xb_tm : xbc[j - 1]);
        float q2prev = (j == 0) ? q2TM : q2c[j - 1];
        float l2prev = (j == 0) ? l2TM : l2c[j - 1];
        float q2m = clampl(q2prev + sigma * gtm, l2prev);

        // adjoint (negative divergence) with NEW q
        float div = (q0m - q0n[j]) + (q1m - q1n[j]) + (q2m - q2n[j]);

        x1v[j] = x0c[j] - tau * (pn[j] + div);
        xbn[j] = x1v[j] + theta * (x1v[j] - x0c[j]);
    }

    *(float4*)(p + off)            = make_float4(pn[0], pn[1], pn[2], pn[3]);
    *(float4*)(qout + q0o)         = make_float4(q0n[0], q0n[1], q0n[2], q0n[3]);
    *(float4*)(qout + q0o + VOL)   = make_float4(q1n[0], q1n[1], q1n[2], q1n[3]);
    *(float4*)(qout + q0o + 2*VOL) = make_float4(q2n[0], q2n[1], q2n[2], q2n[3]);
    *(float4*)(x1out + off)        = make_float4(x1v[0], x1v[1], x1v[2], x1v[3]);
    *(float4*)(xbout + off)        = make_float4(xbn[0], xbn[1], xbn[2], xbn[3]);
}

extern "C" void kernel_launch(void* const* d_in, const int* in_sizes, int n_in,
                              void* d_out, int out_size, void* d_ws, size_t ws_size,
                              hipStream_t stream) {
    const float* x   = (const float*)d_in[0];   // (2,1,160,160,16)
    const float* lam = (const float*)d_in[1];   // (2,3,160,160,16)
    float* out = (float*)d_out;
    float* ws  = (float*)d_ws;

    // ws layout (floats): xbuf | p | xbarA | xbarB | qA | qB  = 8,192,000 f = 32.8 MB
    float* xbuf  = ws;
    float* p     = ws + (size_t)NX;
    float* xbarA = ws + (size_t)2 * NX;
    float* xbarB = ws + (size_t)3 * NX;
    float* qA    = ws + (size_t)4 * NX;
    float* qB    = ws + (size_t)4 * NX + NQ;

    // constants (match reference: sigma = tau = sigmoid(10)/sqrt(13), theta = sigmoid(10))
    const double s10 = 1.0 / (1.0 + exp(-10.0));
    const double L   = sqrt(13.0);
    const float sigma  = (float)(s10 / L);
    const float tau    = sigma;
    const float theta  = (float)s10;
    const float inv1ps = (float)(1.0 / (1.0 + s10 / L));

    init_kernel<<<(NQ + 255) / 256, 256, 0, stream>>>(x, xbuf, p, xbarA, qA);

    const int nthreads = NX / 4;  // 204800
    dim3 grid((nthreads + 255) / 256), block(256);

    for (int it = 0; it < T_ITERS; ++it) {
        const float* qin  = (it & 1) ? qB : qA;
        float*       qout = (it & 1) ? qA : qB;
        const float* xbin = (it & 1) ? xbarB : xbarA;
        float*       xbout= (it & 1) ? xbarA : xbarB;
        float*       x1o  = (it == T_ITERS - 1) ? out : xbuf;  // last iter -> d_out
        step_kernel<<<grid, block, 0, stream>>>(x, p, qin, qout, xbuf, x1o,
                                                xbin, xbout, lam,
                                                sigma, inv1ps, tau, theta);
    }
}